// Round 4
// baseline (7975.835 us; speedup 1.0000x reference)
//
#include <hip/hip_runtime.h>

// ---------------------------------------------------------------------------
// LSTM: B=64, SEQ=512, I=1024, H=1024, O=512, fp32 in/out.
// Row space: n' = hid*4 + gate  (gate-interleaved) so MFMA C-layout puts all
// 4 gate preacts of one (hid,batch) in ONE lane (acc[rr] = gate rr).
//   prep:   pack Wh4/Wx4 -> bf16 [n'=4096][1024], bias[n'], X->bf16,
//           h0 tagged u32 buffer, wT for output GEMM
//   phase1: Xg[t][jb][n'][b16] = X . Wx^T + bias (bf16 MFMA, m97 staging)
//   phase2: persistent recurrence, 128 blocks x 512 thr.
//           R4: tagged-h protocol (bf16|step<<16 per u32, double buffered):
//           consumers poll data directly -> ONE L3 hop per step (R3 had
//           drain + flag store + flag poll + h load). Gate math in-register
//           (no P LDS roundtrip). Xg prefetched a full step early.
//   out:    out[b][o] = h[b,:] . w[o,:]
// ---------------------------------------------------------------------------

typedef short short8 __attribute__((ext_vector_type(8)));   // 8 bf16
typedef float f32x4 __attribute__((ext_vector_type(4)));

typedef __attribute__((address_space(1))) const unsigned int glb_u32;
typedef __attribute__((address_space(3))) unsigned int lds_u32;

#define SEQL  512

__device__ __forceinline__ unsigned short f2bf(float f) {
    unsigned int u = __builtin_bit_cast(unsigned int, f);
    u += 0x7FFFu + ((u >> 16) & 1u);            // round-to-nearest-even
    return (unsigned short)(u >> 16);
}
__device__ __forceinline__ float bf2f(unsigned short s) {
    unsigned int u = ((unsigned int)s) << 16;
    return __builtin_bit_cast(float, u);
}
__device__ __forceinline__ float sigmoidf_fast(float x) {
    return 1.f / (1.f + __expf(-x));
}
__device__ __forceinline__ float tanhf_fast(float x) {
    return 1.f - 2.f / (1.f + __expf(2.f * x));
}
__device__ __forceinline__ void gld_lds16(const unsigned short* g, unsigned short* l) {
    __builtin_amdgcn_global_load_lds((glb_u32*)g, (lds_u32*)l, 16, 0, 0);
}

// --- prep: pack 4 gate weight mats (fp32 [1024][1024]) into bf16 [n'][1024],
//           n' = hid*4 + gate
__global__ void k_pack_w(const float* __restrict__ w0, const float* __restrict__ w1,
                         const float* __restrict__ w2, const float* __restrict__ w3,
                         unsigned short* __restrict__ dst) {
    int idx4 = blockIdx.x * blockDim.x + threadIdx.x;   // over 4096*256
    int np = idx4 >> 8;            // n' 0..4095
    int k4 = (idx4 & 255) * 4;
    int g = np & 3, r = np >> 2;
    const float* src = (g == 0) ? w0 : (g == 1) ? w1 : (g == 2) ? w2 : w3;
    float4 v = *(const float4*)(src + r * 1024 + k4);
    ushort4 o;
    o.x = f2bf(v.x); o.y = f2bf(v.y); o.z = f2bf(v.z); o.w = f2bf(v.w);
    *(ushort4*)(dst + (size_t)np * 1024 + k4) = o;
}

// --- prep: bias[n'], tagged h0 (u32: bf16(h0)|tag0), wT (fp32 [1024][512])
__global__ void k_misc(const float* __restrict__ b_hi, const float* __restrict__ b_xi,
                       const float* __restrict__ b_hf, const float* __restrict__ b_xf,
                       const float* __restrict__ b_ho, const float* __restrict__ b_xo,
                       const float* __restrict__ b_hg, const float* __restrict__ b_xg,
                       const float* __restrict__ h0, const float* __restrict__ w,
                       float* __restrict__ bias, unsigned* __restrict__ hT0,
                       float* __restrict__ wT) {
    int idx = blockIdx.x * blockDim.x + threadIdx.x;
    if (idx < 4096) {
        int g = idx & 3, r = idx >> 2;                  // n'-order bias
        const float* bh = (g == 0) ? b_hi : (g == 1) ? b_hf : (g == 2) ? b_ho : b_hg;
        const float* bx = (g == 0) ? b_xi : (g == 1) ? b_xf : (g == 2) ? b_xo : b_xg;
        bias[idx] = bh[r] + bx[r];
    } else if (idx < 4096 + 65536) {
        int e = idx - 4096;                             // [b][hid], tag = 0
        int k = e & 1023;
        __hip_atomic_store(&hT0[e], (unsigned)f2bf(h0[k]),
                           __ATOMIC_RELAXED, __HIP_MEMORY_SCOPE_AGENT);
    } else if (idx < 4096 + 65536 + 524288) {
        int e = idx - 69632;
        int k = e >> 9, o = e & 511;
        wT[e] = w[o * 1024 + k];
    }
}

// --- prep: X fp32 -> bf16
__global__ void k_convert_x(const float* __restrict__ X, unsigned short* __restrict__ Xb) {
    int idx = blockIdx.x * blockDim.x + threadIdx.x;
    float4 v = ((const float4*)X)[idx];
    ushort4 o;
    o.x = f2bf(v.x); o.y = f2bf(v.y); o.z = f2bf(v.z); o.w = f2bf(v.w);
    ((ushort4*)Xb)[idx] = o;
}

// --- phase 1: Xg[t][jb][n'][b16], 128x128 tiles, m97 staging.
__global__ __launch_bounds__(256) void k_xgemm(const unsigned short* __restrict__ Wx,
                                               const unsigned short* __restrict__ Xb,
                                               const float* __restrict__ bias,
                                               unsigned short* __restrict__ Xg) {
    const int jt = blockIdx.x;          // col tile: t0=jt*2, 64 batches x 2 t
    const int n0 = blockIdx.y * 128;
    const int t0 = jt * 2;
    __shared__ unsigned short At[128 * 32];   // no pad: global_load_lds order
    __shared__ unsigned short Bt[128 * 32];
    const int tid = threadIdx.x;
    const int w   = tid >> 6;
    const int l   = tid & 63;
    const int l15 = l & 15, lq = l >> 4;
    const int wm  = w & 1, wn = w >> 1;
    const int seg = l & 3, cr = w * 16 + (l >> 2);

    const unsigned short* gA0 = Wx + (size_t)(n0 + cr) * 1024 + seg * 8;
    const unsigned short* gA1 = gA0 + (size_t)64 * 1024;
    const unsigned short* gB0 = Xb + ((size_t)cr * 512 + t0) * 1024 + seg * 8;
    const unsigned short* gB1 = gB0 + 1024;
    unsigned short* lA0 = At + w * 512;
    unsigned short* lA1 = At + 2048 + w * 512;
    unsigned short* lB0 = Bt + w * 512;
    unsigned short* lB1 = Bt + 2048 + w * 512;

    f32x4 acc[4][4];
#pragma unroll
    for (int mi = 0; mi < 4; ++mi)
#pragma unroll
        for (int nj = 0; nj < 4; ++nj)
            acc[mi][nj] = f32x4{0.f, 0.f, 0.f, 0.f};

    for (int kk = 0; kk < 32; ++kk) {
        __syncthreads();
        gld_lds16(gA0, lA0);
        gld_lds16(gA1, lA1);
        gld_lds16(gB0, lB0);
        gld_lds16(gB1, lB1);
        gA0 += 32; gA1 += 32; gB0 += 32; gB1 += 32;
        __syncthreads();
        short8 af[4], bfr[4];
#pragma unroll
        for (int mi = 0; mi < 4; ++mi)
            af[mi] = *(const short8*)(At + (wm * 64 + mi * 16 + l15) * 32 + lq * 8);
#pragma unroll
        for (int nj = 0; nj < 4; ++nj)
            bfr[nj] = *(const short8*)(Bt + (wn * 64 + nj * 16 + l15) * 32 + lq * 8);
#pragma unroll
        for (int mi = 0; mi < 4; ++mi)
#pragma unroll
            for (int nj = 0; nj < 4; ++nj)
                acc[mi][nj] = __builtin_amdgcn_mfma_f32_16x16x32_bf16(af[mi], bfr[nj], acc[mi][nj], 0, 0, 0);
    }

    // epilogue: col c = wn*64 + nj*16 + l15 -> t = t0+wn, jb = nj, b16 = l15
#pragma unroll
    for (int mi = 0; mi < 4; ++mi) {
#pragma unroll
        for (int rr = 0; rr < 4; ++rr) {
            int np = n0 + wm * 64 + mi * 16 + lq * 4 + rr;
            float bs = bias[np];
#pragma unroll
            for (int nj = 0; nj < 4; ++nj) {
                size_t idx = ((((size_t)(t0 + wn)) * 4 + nj) * 4096 + np) * 16 + l15;
                Xg[idx] = f2bf(acc[mi][nj][rr] + bs);
            }
        }
    }
}

// --- phase 2: persistent recurrence, tagged-h protocol.
// 128 blocks x 512 thr: jb=blk&3 (16 batches), ibb=blk>>2 (32 hid x 4 gates =
// n' rows [ibb*128, +128)). Wave w: rows ibb*128+w*16..+15. Lane (quad lq,
// l15): acc[rr] = gate rr preact for (hid = ibb*32+w*4+lq, b = jb*16+l15).
__global__ __launch_bounds__(512, 2) void k_rec(const unsigned short* __restrict__ Wh,
                                                const unsigned short* __restrict__ Xg,
                                                const float* __restrict__ c0,
                                                unsigned* __restrict__ h0buf,
                                                unsigned* __restrict__ h1buf) {
    const int blk = blockIdx.x;
    const int jb  = blk & 3;
    const int ibb = blk >> 2;
    const int tid = threadIdx.x;
    const int w   = tid >> 6;
    const int l   = tid & 63;
    const int l15 = l & 15, lq = l >> 4;

    __shared__ unsigned short hTl[16 * 1032];   // [b16][k=1024], stride 1032

    // Persistent A-fragments: rows n' = ibb*128 + w*16 + l15, all K. Pinned.
    short8 afrag[32];
    {
        const unsigned short* wrow = Wh + (size_t)(ibb * 128 + w * 16 + l15) * 1024;
#pragma unroll
        for (int ks = 0; ks < 32; ++ks)
            afrag[ks] = *(const short8*)(wrow + ks * 32 + lq * 8);
#pragma unroll
        for (int ks = 0; ks < 32; ++ks)
            asm volatile("" : "+v"(afrag[ks]));
    }

    const int hid = ibb * 32 + w * 4 + lq;     // this lane's hidden unit
    const int bat = jb * 16 + l15;             // this lane's batch
    float c = c0[hid];

    // poll/stage mapping: thread -> (batch row sb, 32-hid chunk sh)
    const int sb = tid >> 5;
    const int sh = (tid & 31) * 32;
    const unsigned long long* poll0 =
        (const unsigned long long*)h0buf + (((size_t)(jb * 16 + sb) * 1024 + sh) >> 1);
    const unsigned long long* poll1 =
        (const unsigned long long*)h1buf + (((size_t)(jb * 16 + sb) * 1024 + sh) >> 1);

    // Xg index for (t, rr): ((t*4 + jb)*4096 + ibb*128 + w*16 + lq*4 + rr)*16 + l15
    const size_t xg_row = (size_t)ibb * 128 + w * 16 + lq * 4;
    const size_t xg_fix = xg_row * 16 + l15;

    float xg[4];
#pragma unroll
    for (int rr = 0; rr < 4; ++rr)
        xg[rr] = bf2f(Xg[((size_t)jb * 4096 + rr) * 16 + xg_fix]);   // t = 0

    for (int t = 0; t < SEQL; ++t) {
        unsigned* hdst = (t & 1) ? h0buf : h1buf;
        const unsigned long long* src64 = (t & 1) ? poll1 : poll0;

        // prefetch next-step Xg immediately (full step of latency cover)
        float xgn[4];
        {
            int tn = (t < SEQL - 1) ? t + 1 : t;
            size_t base = (((size_t)tn * 4 + jb) * 4096) * 16 + xg_fix;
#pragma unroll
            for (int rr = 0; rr < 4; ++rr)
                xgn[rr] = bf2f(Xg[base + (size_t)rr * 16]);
        }

        // poll tagged h words (expect tag == t), reloading only stale slots
        unsigned long long v[16];
        const unsigned exp = (unsigned)t;
        unsigned stale = 0xFFFFu;
        do {
#pragma unroll
            for (int s = 0; s < 16; ++s)
                if (stale & (1u << s))
                    v[s] = __hip_atomic_load(src64 + s, __ATOMIC_RELAXED,
                                             __HIP_MEMORY_SCOPE_AGENT);
            unsigned ns = 0;
#pragma unroll
            for (int s = 0; s < 16; ++s) {
                unsigned tg0 = (unsigned)(v[s] >> 16) & 0xFFFFu;
                unsigned tg1 = (unsigned)(v[s] >> 48);
                if ((tg0 != exp) | (tg1 != exp)) ns |= (1u << s);
            }
            stale = ns;
        } while (stale);

        // pack 32 bf16 -> LDS [sb][sh..sh+31]
        {
            unsigned packed[16];
#pragma unroll
            for (int s = 0; s < 16; ++s)
                packed[s] = ((unsigned)v[s] & 0xFFFFu) |
                            (((unsigned)(v[s] >> 32) & 0xFFFFu) << 16);
            uint4* dstl = (uint4*)(&hTl[sb * 1032 + sh]);
#pragma unroll
            for (int q = 0; q < 4; ++q)
                dstl[q] = uint4{packed[q * 4], packed[q * 4 + 1],
                                packed[q * 4 + 2], packed[q * 4 + 3]};
        }
        __syncthreads();

        // MFMA over K=1024, two independent chains
        f32x4 acc0 = {0.f, 0.f, 0.f, 0.f}, acc1 = {0.f, 0.f, 0.f, 0.f};
#pragma unroll
        for (int ks = 0; ks < 32; ks += 2) {
            short8 b0 = *(const short8*)(&hTl[l15 * 1032 + ks * 32 + lq * 8]);
            short8 b1 = *(const short8*)(&hTl[l15 * 1032 + (ks + 1) * 32 + lq * 8]);
            acc0 = __builtin_amdgcn_mfma_f32_16x16x32_bf16(afrag[ks], b0, acc0, 0, 0, 0);
            acc1 = __builtin_amdgcn_mfma_f32_16x16x32_bf16(afrag[ks + 1], b1, acc1, 0, 0, 0);
        }
        __syncthreads();   // all ds_reads done before next stage overwrites hTl

        // in-register gate math: acc[rr] = gate rr for (hid, bat)
        {
            float pi = acc0[0] + acc1[0] + xg[0];
            float pf = acc0[1] + acc1[1] + xg[1];
            float po = acc0[2] + acc1[2] + xg[2];
            float pg = acc0[3] + acc1[3] + xg[3];
            float ig = sigmoidf_fast(pi);
            float fg = sigmoidf_fast(pf);
            float og = sigmoidf_fast(po);
            float gg = tanhf_fast(pg);
            c = fg * c + ig * gg;
            float hh = og * tanhf_fast(c);
            unsigned word = (unsigned)f2bf(hh) | ((unsigned)(t + 1) << 16);
            __hip_atomic_store(hdst + (size_t)bat * 1024 + hid, word,
                               __ATOMIC_RELAXED, __HIP_MEMORY_SCOPE_AGENT);
        }
#pragma unroll
        for (int rr = 0; rr < 4; ++rr) xg[rr] = xgn[rr];
    }
    // t=511 writes hdst = h0buf (tags 512): final h in h0buf
}

// --- output: out[b][o] = sum_k h[b][k] * w[o][k]; h from tagged u32 buffer
__global__ __launch_bounds__(256) void k_out(const unsigned* __restrict__ hT,
                                             const float* __restrict__ wT,
                                             float* __restrict__ out) {
    const int b = blockIdx.x;
    const int tid = threadIdx.x;
    __shared__ float hs[1024];
#pragma unroll
    for (int p = 0; p < 4; ++p)
        hs[p * 256 + tid] = bf2f((unsigned short)(hT[b * 1024 + p * 256 + tid] & 0xFFFFu));
    __syncthreads();
    float a0 = 0.f, a1 = 0.f;
    for (int k = 0; k < 1024; ++k) {
        float hv = hs[k];
        a0 = fmaf(hv, wT[k * 512 + tid], a0);
        a1 = fmaf(hv, wT[k * 512 + 256 + tid], a1);
    }
    out[b * 512 + tid] = a0;
    out[b * 512 + 256 + tid] = a1;
}

extern "C" void kernel_launch(void* const* d_in, const int* in_sizes, int n_in,
                              void* d_out, int out_size, void* d_ws, size_t ws_size,
                              hipStream_t stream) {
    const float* X    = (const float*)d_in[0];
    const float* c0   = (const float*)d_in[1];
    const float* h0   = (const float*)d_in[2];
    const float* w_hi = (const float*)d_in[3];
    const float* w_xi = (const float*)d_in[4];
    const float* b_hi = (const float*)d_in[5];
    const float* b_xi = (const float*)d_in[6];
    const float* w_hf = (const float*)d_in[7];
    const float* w_xf = (const float*)d_in[8];
    const float* b_hf = (const float*)d_in[9];
    const float* b_xf = (const float*)d_in[10];
    const float* w_ho = (const float*)d_in[11];
    const float* w_xo = (const float*)d_in[12];
    const float* b_ho = (const float*)d_in[13];
    const float* b_xo = (const float*)d_in[14];
    const float* w_hg = (const float*)d_in[15];
    const float* w_xg = (const float*)d_in[16];
    const float* b_hg = (const float*)d_in[17];
    const float* b_xg = (const float*)d_in[18];
    const float* w    = (const float*)d_in[19];

    // workspace layout (16B aligned); ~339 MiB
    char* ws = (char*)d_ws;
    size_t off = 0;
    unsigned short* Xg  = (unsigned short*)(ws + off); off += (size_t)512 * 4096 * 64 * 2;
    unsigned short* Whp = (unsigned short*)(ws + off); off += (size_t)4096 * 1024 * 2;
    unsigned short* Wxp = (unsigned short*)(ws + off); off += (size_t)4096 * 1024 * 2;
    unsigned short* Xb  = (unsigned short*)(ws + off); off += (size_t)64 * 512 * 1024 * 2;
    float*          bias= (float*)(ws + off);          off += (size_t)4096 * 4;
    float*          wT  = (float*)(ws + off);          off += (size_t)1024 * 512 * 4;
    unsigned*       hT0 = (unsigned*)(ws + off);       off += (size_t)64 * 1024 * 4;
    unsigned*       hT1 = (unsigned*)(ws + off);       off += (size_t)64 * 1024 * 4;
    if (ws_size < off) return;

    k_pack_w<<<4096, 256, 0, stream>>>(w_hi, w_hf, w_ho, w_hg, Whp);
    k_pack_w<<<4096, 256, 0, stream>>>(w_xi, w_xf, w_xo, w_xg, Wxp);
    k_misc<<<(4096 + 65536 + 524288 + 255) / 256, 256, 0, stream>>>(
        b_hi, b_xi, b_hf, b_xf, b_ho, b_xo, b_hg, b_xg, h0, w, bias, hT0, wT);
    k_convert_x<<<33554432 / 4 / 256, 256, 0, stream>>>(X, Xb);

    k_xgemm<<<dim3(256, 32), 256, 0, stream>>>(Wxp, Xb, bias, Xg);

    void* args[] = {(void*)&Whp, (void*)&Xg, (void*)&c0, (void*)&hT0, (void*)&hT1};
    hipLaunchCooperativeKernel((void*)k_rec, dim3(128), dim3(512), args, 0, stream);

    k_out<<<64, 256, 0, stream>>>(hT0, wT, (float*)d_out);
}

// Round 5
// 2456.370 us; speedup vs baseline: 3.2470x; 3.2470x over previous
//
#include <hip/hip_runtime.h>

// ---------------------------------------------------------------------------
// LSTM: B=64, SEQ=512, I=1024, H=1024, O=512, fp32 in/out.
// Row space: n' = hid*4 + gate (gate-interleaved) so MFMA C-layout puts all
// 4 gate preacts of one (hid,batch) in ONE lane (acc[rr] = gate rr).
//   prep:   pack Wh4/Wx4 -> bf16 [n'=4096][1024], bias[n'], X->bf16,
//           h0 bf16 buffer, wT for output GEMM, zero barrier flags
//   phase1: Xg[t][jb][n'][b16] = X . Wx^T + bias (bf16 MFMA, m97 staging)
//   phase2: persistent recurrence, 128 blocks x 512 thr.
//           R5 = R3 skeleton (flag barrier + coalesced h exchange + LDS h
//           staging) + gate-interleave in-register gate math + packed Xg +
//           Xg prefetch moved after flag store (drain no longer waits on it).
//           R4's per-word tagged protocol REVERTED: scattered 4B sc-stores
//           went write-through to HBM (WRITE_SIZE 67->262MB, 4x regression).
//   out:    out[b][o] = h[b,:] . w[o,:]
// ---------------------------------------------------------------------------

typedef short short8 __attribute__((ext_vector_type(8)));   // 8 bf16
typedef float f32x4 __attribute__((ext_vector_type(4)));

typedef __attribute__((address_space(1))) const unsigned int glb_u32;
typedef __attribute__((address_space(3))) unsigned int lds_u32;

#define SEQL  512

// Barrier flags: [group jb 0..3][block-in-group 0..31], one 128B line/group.
__device__ __attribute__((aligned(128))) unsigned g_bars[128];

__device__ __forceinline__ unsigned short f2bf(float f) {
    unsigned int u = __builtin_bit_cast(unsigned int, f);
    u += 0x7FFFu + ((u >> 16) & 1u);            // round-to-nearest-even
    return (unsigned short)(u >> 16);
}
__device__ __forceinline__ float bf2f(unsigned short s) {
    unsigned int u = ((unsigned int)s) << 16;
    return __builtin_bit_cast(float, u);
}
__device__ __forceinline__ float sigmoidf_fast(float x) {
    return 1.f / (1.f + __expf(-x));
}
__device__ __forceinline__ float tanhf_fast(float x) {
    return 1.f - 2.f / (1.f + __expf(2.f * x));
}
__device__ __forceinline__ void gld_lds16(const unsigned short* g, unsigned short* l) {
    __builtin_amdgcn_global_load_lds((glb_u32*)g, (lds_u32*)l, 16, 0, 0);
}

// --- prep: pack 4 gate weight mats (fp32 [1024][1024]) into bf16 [n'][1024]
__global__ void k_pack_w(const float* __restrict__ w0, const float* __restrict__ w1,
                         const float* __restrict__ w2, const float* __restrict__ w3,
                         unsigned short* __restrict__ dst) {
    int idx4 = blockIdx.x * blockDim.x + threadIdx.x;   // over 4096*256
    int np = idx4 >> 8;            // n' 0..4095
    int k4 = (idx4 & 255) * 4;
    int g = np & 3, r = np >> 2;
    const float* src = (g == 0) ? w0 : (g == 1) ? w1 : (g == 2) ? w2 : w3;
    float4 v = *(const float4*)(src + r * 1024 + k4);
    ushort4 o;
    o.x = f2bf(v.x); o.y = f2bf(v.y); o.z = f2bf(v.z); o.w = f2bf(v.w);
    *(ushort4*)(dst + (size_t)np * 1024 + k4) = o;
}

// --- prep: bias[n'], h0 bf16 [64][1024], wT (fp32 [1024][512]), zero flags
__global__ void k_misc(const float* __restrict__ b_hi, const float* __restrict__ b_xi,
                       const float* __restrict__ b_hf, const float* __restrict__ b_xf,
                       const float* __restrict__ b_ho, const float* __restrict__ b_xo,
                       const float* __restrict__ b_hg, const float* __restrict__ b_xg,
                       const float* __restrict__ h0, const float* __restrict__ w,
                       float* __restrict__ bias, unsigned short* __restrict__ hT0,
                       float* __restrict__ wT) {
    int idx = blockIdx.x * blockDim.x + threadIdx.x;
    if (idx < 4096) {
        int g = idx & 3, r = idx >> 2;                  // n'-order bias
        const float* bh = (g == 0) ? b_hi : (g == 1) ? b_hf : (g == 2) ? b_ho : b_hg;
        const float* bx = (g == 0) ? b_xi : (g == 1) ? b_xf : (g == 2) ? b_xo : b_xg;
        bias[idx] = bh[r] + bx[r];
    } else if (idx < 4096 + 65536) {
        int e = idx - 4096;                             // [b][hid]
        int k = e & 1023;
        hT0[e] = f2bf(h0[k]);
    } else if (idx < 4096 + 65536 + 524288) {
        int e = idx - 69632;
        int k = e >> 9, o = e & 511;
        wT[e] = w[o * 1024 + k];
    } else if (idx < 4096 + 65536 + 524288 + 128) {
        int e = idx - (4096 + 65536 + 524288);
        __hip_atomic_store(&g_bars[e], 0u, __ATOMIC_RELAXED, __HIP_MEMORY_SCOPE_AGENT);
    }
}

// --- prep: X fp32 -> bf16
__global__ void k_convert_x(const float* __restrict__ X, unsigned short* __restrict__ Xb) {
    int idx = blockIdx.x * blockDim.x + threadIdx.x;
    float4 v = ((const float4*)X)[idx];
    ushort4 o;
    o.x = f2bf(v.x); o.y = f2bf(v.y); o.z = f2bf(v.z); o.w = f2bf(v.w);
    ((ushort4*)Xb)[idx] = o;
}

// --- phase 1: Xg[t][jb][n'][b16], 128x128 tiles, m97 staging.
__global__ __launch_bounds__(256) void k_xgemm(const unsigned short* __restrict__ Wx,
                                               const unsigned short* __restrict__ Xb,
                                               const float* __restrict__ bias,
                                               unsigned short* __restrict__ Xg) {
    const int jt = blockIdx.x;          // col tile: t0=jt*2, 64 batches x 2 t
    const int n0 = blockIdx.y * 128;
    const int t0 = jt * 2;
    __shared__ unsigned short At[128 * 32];   // no pad: global_load_lds order
    __shared__ unsigned short Bt[128 * 32];
    const int tid = threadIdx.x;
    const int w   = tid >> 6;
    const int l   = tid & 63;
    const int l15 = l & 15, lq = l >> 4;
    const int wm  = w & 1, wn = w >> 1;
    const int seg = l & 3, cr = w * 16 + (l >> 2);

    const unsigned short* gA0 = Wx + (size_t)(n0 + cr) * 1024 + seg * 8;
    const unsigned short* gA1 = gA0 + (size_t)64 * 1024;
    const unsigned short* gB0 = Xb + ((size_t)cr * 512 + t0) * 1024 + seg * 8;
    const unsigned short* gB1 = gB0 + 1024;
    unsigned short* lA0 = At + w * 512;
    unsigned short* lA1 = At + 2048 + w * 512;
    unsigned short* lB0 = Bt + w * 512;
    unsigned short* lB1 = Bt + 2048 + w * 512;

    f32x4 acc[4][4];
#pragma unroll
    for (int mi = 0; mi < 4; ++mi)
#pragma unroll
        for (int nj = 0; nj < 4; ++nj)
            acc[mi][nj] = f32x4{0.f, 0.f, 0.f, 0.f};

    for (int kk = 0; kk < 32; ++kk) {
        __syncthreads();
        gld_lds16(gA0, lA0);
        gld_lds16(gA1, lA1);
        gld_lds16(gB0, lB0);
        gld_lds16(gB1, lB1);
        gA0 += 32; gA1 += 32; gB0 += 32; gB1 += 32;
        __syncthreads();
        short8 af[4], bfr[4];
#pragma unroll
        for (int mi = 0; mi < 4; ++mi)
            af[mi] = *(const short8*)(At + (wm * 64 + mi * 16 + l15) * 32 + lq * 8);
#pragma unroll
        for (int nj = 0; nj < 4; ++nj)
            bfr[nj] = *(const short8*)(Bt + (wn * 64 + nj * 16 + l15) * 32 + lq * 8);
#pragma unroll
        for (int mi = 0; mi < 4; ++mi)
#pragma unroll
            for (int nj = 0; nj < 4; ++nj)
                acc[mi][nj] = __builtin_amdgcn_mfma_f32_16x16x32_bf16(af[mi], bfr[nj], acc[mi][nj], 0, 0, 0);
    }

    // epilogue: col c = wn*64 + nj*16 + l15 -> t = t0+wn, jb = nj, b16 = l15
#pragma unroll
    for (int mi = 0; mi < 4; ++mi) {
#pragma unroll
        for (int rr = 0; rr < 4; ++rr) {
            int np = n0 + wm * 64 + mi * 16 + lq * 4 + rr;
            float bs = bias[np];
#pragma unroll
            for (int nj = 0; nj < 4; ++nj) {
                size_t idx = ((((size_t)(t0 + wn)) * 4 + nj) * 4096 + np) * 16 + l15;
                Xg[idx] = f2bf(acc[mi][nj][rr] + bs);
            }
        }
    }
}

// --- phase 2: persistent recurrence (R3 protocol + gate-interleave).
// 128 blocks x 512 thr: jb=blk&3 (16 batches), ibb=blk>>2 (n' rows
// [ibb*128,+128) = 32 hids x 4 gates). Wave w: rows ibb*128+w*16+[0,16).
// Lane (lq,l15): acc[rr] = gate-rr preact for hid=ibb*32+w*4+lq, b=jb*16+l15.
__global__ __launch_bounds__(512, 2) void k_rec(const unsigned short* __restrict__ Wh,
                                                const unsigned short* __restrict__ Xg,
                                                const float* __restrict__ c0,
                                                unsigned short* __restrict__ h0buf,
                                                unsigned short* __restrict__ h1buf) {
    const int blk = blockIdx.x;
    const int jb  = blk & 3;
    const int ibb = blk >> 2;
    const int tid = threadIdx.x;
    const int w   = tid >> 6;
    const int l   = tid & 63;
    const int l15 = l & 15, lq = l >> 4;

    __shared__ unsigned short hTl[16 * 1032];   // [b16][k=1024], stride 1032
    __shared__ unsigned short hTr[16 * 36];     // h transpose [b16][hid32], pad 36

    // Persistent A-fragments: rows n' = ibb*128 + w*16 + l15, all K.
    // (R3 evidence: pinned frags land in AGPRs; MFMA reads AGPR A-ops free.)
    short8 afrag[32];
    {
        const unsigned short* wrow = Wh + (size_t)(ibb * 128 + w * 16 + l15) * 1024;
#pragma unroll
        for (int ks = 0; ks < 32; ++ks)
            afrag[ks] = *(const short8*)(wrow + ks * 32 + lq * 8);
#pragma unroll
        for (int ks = 0; ks < 32; ++ks)
            asm volatile("" : "+v"(afrag[ks]));
    }

    const int hid = ibb * 32 + w * 4 + lq;     // this lane's hidden unit
    float c = c0[hid];

    // h staging mapping: thread -> (batch row sb, u64 lane sln)
    const int sb = tid >> 5, sln = tid & 31;
    const unsigned long long* poll0 =
        (const unsigned long long*)h0buf + (size_t)(jb * 16 + sb) * 256;
    const unsigned long long* poll1 =
        (const unsigned long long*)h1buf + (size_t)(jb * 16 + sb) * 256;

    // Xg fixed part: (( (t*4+jb)*4096 + ibb*128 + w*16 + lq*4 + rr )*16 + l15
    const size_t xg_fix = ((size_t)ibb * 128 + w * 16 + lq * 4) * 16 + l15;

    float xg[4];
#pragma unroll
    for (int rr = 0; rr < 4; ++rr)
        xg[rr] = bf2f(Xg[((size_t)jb * 4096 + rr) * 16 + xg_fix]);   // t = 0

    for (int t = 0; t < SEQL; ++t) {
        const unsigned long long* src64 = (t & 1) ? poll1 : poll0;
        unsigned short* hdst = (t & 1) ? h0buf : h1buf;

        // --- barrier wait: producers of h_t have flags >= t ---
        if (tid < 64) {
            bool ok;
            do {
                unsigned v = __hip_atomic_load(&g_bars[jb * 32 + (tid & 31)],
                                               __ATOMIC_RELAXED, __HIP_MEMORY_SCOPE_AGENT);
                ok = (tid >= 32) || (v >= (unsigned)t);
            } while (!__all(ok));
        }
        __syncthreads();

        // --- stage h slice (16 batches x 1024 k) into LDS, coalesced ---
        {
            unsigned long long tmp[8];
#pragma unroll
            for (int p = 0; p < 8; ++p)
                tmp[p] = __hip_atomic_load(src64 + p * 32 + sln,
                                           __ATOMIC_RELAXED, __HIP_MEMORY_SCOPE_AGENT);
#pragma unroll
            for (int p = 0; p < 8; ++p)
                *(unsigned long long*)(&hTl[sb * 1032 + (p * 32 + sln) * 4]) = tmp[p];
        }
        __syncthreads();

        // --- MFMA over K=1024, two chains ---
        f32x4 acc0 = {0.f, 0.f, 0.f, 0.f}, acc1 = {0.f, 0.f, 0.f, 0.f};
#pragma unroll
        for (int ks = 0; ks < 32; ks += 2) {
            short8 b0 = *(const short8*)(&hTl[l15 * 1032 + ks * 32 + lq * 8]);
            short8 b1 = *(const short8*)(&hTl[l15 * 1032 + (ks + 1) * 32 + lq * 8]);
            acc0 = __builtin_amdgcn_mfma_f32_16x16x32_bf16(afrag[ks], b0, acc0, 0, 0, 0);
            acc1 = __builtin_amdgcn_mfma_f32_16x16x32_bf16(afrag[ks + 1], b1, acc1, 0, 0, 0);
        }

        // --- in-register gate math; h -> LDS transpose buffer ---
        {
            float pi = acc0[0] + acc1[0] + xg[0];
            float pf = acc0[1] + acc1[1] + xg[1];
            float po = acc0[2] + acc1[2] + xg[2];
            float pg = acc0[3] + acc1[3] + xg[3];
            float ig = sigmoidf_fast(pi);
            float fg = sigmoidf_fast(pf);
            float og = sigmoidf_fast(po);
            float gg = tanhf_fast(pg);
            c = fg * c + ig * gg;
            float hh = og * tanhf_fast(c);
            hTr[l15 * 36 + w * 4 + lq] = f2bf(hh);
        }
        __syncthreads();    // hTr complete; also protects hTl reuse next iter

        // --- coalesced h store: 16 rows x 64B, 128 threads x 8B ---
        if (tid < 128) {
            int row = tid >> 3, seg = tid & 7;
            unsigned long long v = *(const unsigned long long*)(&hTr[row * 36 + seg * 4]);
            unsigned long long* dst = (unsigned long long*)hdst +
                (((size_t)(jb * 16 + row) * 1024 + ibb * 32 + seg * 4) >> 2);
            __hip_atomic_store(dst, v, __ATOMIC_RELAXED, __HIP_MEMORY_SCOPE_AGENT);
        }
        asm volatile("s_waitcnt vmcnt(0)" ::: "memory");  // h stores at L3
        __syncthreads();                                   // all stores drained

        // --- flag arrival, then Xg prefetch overlapping next poll ---
        if (tid == 0)
            __hip_atomic_store(&g_bars[jb * 32 + ibb], (unsigned)(t + 1),
                               __ATOMIC_RELAXED, __HIP_MEMORY_SCOPE_AGENT);
        {
            int tn = (t < SEQL - 1) ? t + 1 : t;
            size_t base = (((size_t)tn * 4 + jb) * 4096) * 16 + xg_fix;
#pragma unroll
            for (int rr = 0; rr < 4; ++rr)
                xg[rr] = bf2f(Xg[base + (size_t)rr * 16]);
        }
    }
    // t=511 writes hdst = h0buf: final h in h0buf
}

// --- output: out[b][o] = sum_k h[b][k] * w[o][k]
__global__ __launch_bounds__(256) void k_out(const unsigned short* __restrict__ hT,
                                             const float* __restrict__ wT,
                                             float* __restrict__ out) {
    const int b = blockIdx.x;
    const int tid = threadIdx.x;
    __shared__ float hs[1024];
#pragma unroll
    for (int p = 0; p < 4; ++p)
        hs[p * 256 + tid] = bf2f(hT[b * 1024 + p * 256 + tid]);
    __syncthreads();
    float a0 = 0.f, a1 = 0.f;
    for (int k = 0; k < 1024; ++k) {
        float hv = hs[k];
        a0 = fmaf(hv, wT[k * 512 + tid], a0);
        a1 = fmaf(hv, wT[k * 512 + 256 + tid], a1);
    }
    out[b * 512 + tid] = a0;
    out[b * 512 + 256 + tid] = a1;
}

extern "C" void kernel_launch(void* const* d_in, const int* in_sizes, int n_in,
                              void* d_out, int out_size, void* d_ws, size_t ws_size,
                              hipStream_t stream) {
    const float* X    = (const float*)d_in[0];
    const float* c0   = (const float*)d_in[1];
    const float* h0   = (const float*)d_in[2];
    const float* w_hi = (const float*)d_in[3];
    const float* w_xi = (const float*)d_in[4];
    const float* b_hi = (const float*)d_in[5];
    const float* b_xi = (const float*)d_in[6];
    const float* w_hf = (const float*)d_in[7];
    const float* w_xf = (const float*)d_in[8];
    const float* b_hf = (const float*)d_in[9];
    const float* b_xf = (const float*)d_in[10];
    const float* w_ho = (const float*)d_in[11];
    const float* w_xo = (const float*)d_in[12];
    const float* b_ho = (const float*)d_in[13];
    const float* b_xo = (const float*)d_in[14];
    const float* w_hg = (const float*)d_in[15];
    const float* w_xg = (const float*)d_in[16];
    const float* b_hg = (const float*)d_in[17];
    const float* b_xg = (const float*)d_in[18];
    const float* w    = (const float*)d_in[19];

    // workspace layout (16B aligned); ~338 MiB
    char* ws = (char*)d_ws;
    size_t off = 0;
    unsigned short* Xg  = (unsigned short*)(ws + off); off += (size_t)512 * 4096 * 64 * 2;
    unsigned short* Whp = (unsigned short*)(ws + off); off += (size_t)4096 * 1024 * 2;
    unsigned short* Wxp = (unsigned short*)(ws + off); off += (size_t)4096 * 1024 * 2;
    unsigned short* Xb  = (unsigned short*)(ws + off); off += (size_t)64 * 512 * 1024 * 2;
    float*          bias= (float*)(ws + off);          off += (size_t)4096 * 4;
    float*          wT  = (float*)(ws + off);          off += (size_t)1024 * 512 * 4;
    unsigned short* hT0 = (unsigned short*)(ws + off); off += (size_t)64 * 1024 * 2;
    unsigned short* hT1 = (unsigned short*)(ws + off); off += (size_t)64 * 1024 * 2;
    if (ws_size < off) return;

    k_pack_w<<<4096, 256, 0, stream>>>(w_hi, w_hf, w_ho, w_hg, Whp);
    k_pack_w<<<4096, 256, 0, stream>>>(w_xi, w_xf, w_xo, w_xg, Wxp);
    k_misc<<<(4096 + 65536 + 524288 + 128 + 255) / 256, 256, 0, stream>>>(
        b_hi, b_xi, b_hf, b_xf, b_ho, b_xo, b_hg, b_xg, h0, w, bias, hT0, wT);
    k_convert_x<<<33554432 / 4 / 256, 256, 0, stream>>>(X, Xb);

    k_xgemm<<<dim3(256, 32), 256, 0, stream>>>(Wxp, Xb, bias, Xg);

    void* args[] = {(void*)&Whp, (void*)&Xg, (void*)&c0, (void*)&hT0, (void*)&hT1};
    hipLaunchCooperativeKernel((void*)k_rec, dim3(128), dim3(512), args, 0, stream);

    k_out<<<64, 256, 0, stream>>>(hT0, wT, (float*)d_out);
}

// Round 6
// 2375.443 us; speedup vs baseline: 3.3576x; 1.0341x over previous
//
#include <hip/hip_runtime.h>

// ---------------------------------------------------------------------------
// LSTM: B=64, SEQ=512, I=1024, H=1024, O=512, fp32 in/out.
// Row space: n' = hid*4 + gate (gate-interleaved) so MFMA C-layout puts all
// 4 gate preacts of one (hid,batch) in ONE lane (acc[rr] = gate rr).
//   prep:   pack Wh4/Wx4 -> bf16 [n'=4096][1024], bias[n'], X->bf16,
//           h0 bf16 buffer, wT for output GEMM, zero barrier counters
//   phase1: Xg[t][jb][n'][b16] = X . Wx^T + bias (bf16 MFMA, m97 staging)
//   phase2: persistent recurrence, 128 blocks x 512 thr.
//           R6 = R5 + aggregated epoch-counter barrier. R5 evidence: fixing
//           Xg overfetch (FETCH 606->213MB) left time unchanged -> step is
//           latency/contention-bound, not traffic-bound. R5's poll was
//           2048 lanes/group hammering one 128B flag line (L3 slice
//           serializes -> ~the whole 3.4us step). Now: producers fetch_add
//           one counter (1 lane/block), consumer polls with 1 lane/block +
//           s_sleep backoff. ~64x less pressure on the hot line.
//   out:    out[b][o] = h[b,:] . w[o,:]
// ---------------------------------------------------------------------------

typedef short short8 __attribute__((ext_vector_type(8)));   // 8 bf16
typedef float f32x4 __attribute__((ext_vector_type(4)));

typedef __attribute__((address_space(1))) const unsigned int glb_u32;
typedef __attribute__((address_space(3))) unsigned int lds_u32;

#define SEQL  512

// Epoch counters: one per batch-group jb, each on its own 128B line.
__device__ __attribute__((aligned(128))) unsigned g_bars[128];

__device__ __forceinline__ unsigned short f2bf(float f) {
    unsigned int u = __builtin_bit_cast(unsigned int, f);
    u += 0x7FFFu + ((u >> 16) & 1u);            // round-to-nearest-even
    return (unsigned short)(u >> 16);
}
__device__ __forceinline__ float bf2f(unsigned short s) {
    unsigned int u = ((unsigned int)s) << 16;
    return __builtin_bit_cast(float, u);
}
__device__ __forceinline__ float sigmoidf_fast(float x) {
    return 1.f / (1.f + __expf(-x));
}
__device__ __forceinline__ float tanhf_fast(float x) {
    return 1.f - 2.f / (1.f + __expf(2.f * x));
}
__device__ __forceinline__ void gld_lds16(const unsigned short* g, unsigned short* l) {
    __builtin_amdgcn_global_load_lds((glb_u32*)g, (lds_u32*)l, 16, 0, 0);
}

// --- prep: pack 4 gate weight mats (fp32 [1024][1024]) into bf16 [n'][1024]
__global__ void k_pack_w(const float* __restrict__ w0, const float* __restrict__ w1,
                         const float* __restrict__ w2, const float* __restrict__ w3,
                         unsigned short* __restrict__ dst) {
    int idx4 = blockIdx.x * blockDim.x + threadIdx.x;   // over 4096*256
    int np = idx4 >> 8;            // n' 0..4095
    int k4 = (idx4 & 255) * 4;
    int g = np & 3, r = np >> 2;
    const float* src = (g == 0) ? w0 : (g == 1) ? w1 : (g == 2) ? w2 : w3;
    float4 v = *(const float4*)(src + r * 1024 + k4);
    ushort4 o;
    o.x = f2bf(v.x); o.y = f2bf(v.y); o.z = f2bf(v.z); o.w = f2bf(v.w);
    *(ushort4*)(dst + (size_t)np * 1024 + k4) = o;
}

// --- prep: bias[n'], h0 bf16 [64][1024], wT (fp32 [1024][512]), zero counters
__global__ void k_misc(const float* __restrict__ b_hi, const float* __restrict__ b_xi,
                       const float* __restrict__ b_hf, const float* __restrict__ b_xf,
                       const float* __restrict__ b_ho, const float* __restrict__ b_xo,
                       const float* __restrict__ b_hg, const float* __restrict__ b_xg,
                       const float* __restrict__ h0, const float* __restrict__ w,
                       float* __restrict__ bias, unsigned short* __restrict__ hT0,
                       float* __restrict__ wT) {
    int idx = blockIdx.x * blockDim.x + threadIdx.x;
    if (idx < 4096) {
        int g = idx & 3, r = idx >> 2;                  // n'-order bias
        const float* bh = (g == 0) ? b_hi : (g == 1) ? b_hf : (g == 2) ? b_ho : b_hg;
        const float* bx = (g == 0) ? b_xi : (g == 1) ? b_xf : (g == 2) ? b_xo : b_xg;
        bias[idx] = bh[r] + bx[r];
    } else if (idx < 4096 + 65536) {
        int e = idx - 4096;                             // [b][hid]
        int k = e & 1023;
        hT0[e] = f2bf(h0[k]);
    } else if (idx < 4096 + 65536 + 524288) {
        int e = idx - 69632;
        int k = e >> 9, o = e & 511;
        wT[e] = w[o * 1024 + k];
    } else if (idx < 4096 + 65536 + 524288 + 128) {
        int e = idx - (4096 + 65536 + 524288);
        __hip_atomic_store(&g_bars[e], 0u, __ATOMIC_RELAXED, __HIP_MEMORY_SCOPE_AGENT);
    }
}

// --- prep: X fp32 -> bf16
__global__ void k_convert_x(const float* __restrict__ X, unsigned short* __restrict__ Xb) {
    int idx = blockIdx.x * blockDim.x + threadIdx.x;
    float4 v = ((const float4*)X)[idx];
    ushort4 o;
    o.x = f2bf(v.x); o.y = f2bf(v.y); o.z = f2bf(v.z); o.w = f2bf(v.w);
    ((ushort4*)Xb)[idx] = o;
}

// --- phase 1: Xg[t][jb][n'][b16], 128x128 tiles, m97 staging.
__global__ __launch_bounds__(256) void k_xgemm(const unsigned short* __restrict__ Wx,
                                               const unsigned short* __restrict__ Xb,
                                               const float* __restrict__ bias,
                                               unsigned short* __restrict__ Xg) {
    const int jt = blockIdx.x;          // col tile: t0=jt*2, 64 batches x 2 t
    const int n0 = blockIdx.y * 128;
    const int t0 = jt * 2;
    __shared__ unsigned short At[128 * 32];   // no pad: global_load_lds order
    __shared__ unsigned short Bt[128 * 32];
    const int tid = threadIdx.x;
    const int w   = tid >> 6;
    const int l   = tid & 63;
    const int l15 = l & 15, lq = l >> 4;
    const int wm  = w & 1, wn = w >> 1;
    const int seg = l & 3, cr = w * 16 + (l >> 2);

    const unsigned short* gA0 = Wx + (size_t)(n0 + cr) * 1024 + seg * 8;
    const unsigned short* gA1 = gA0 + (size_t)64 * 1024;
    const unsigned short* gB0 = Xb + ((size_t)cr * 512 + t0) * 1024 + seg * 8;
    const unsigned short* gB1 = gB0 + 1024;
    unsigned short* lA0 = At + w * 512;
    unsigned short* lA1 = At + 2048 + w * 512;
    unsigned short* lB0 = Bt + w * 512;
    unsigned short* lB1 = Bt + 2048 + w * 512;

    f32x4 acc[4][4];
#pragma unroll
    for (int mi = 0; mi < 4; ++mi)
#pragma unroll
        for (int nj = 0; nj < 4; ++nj)
            acc[mi][nj] = f32x4{0.f, 0.f, 0.f, 0.f};

    for (int kk = 0; kk < 32; ++kk) {
        __syncthreads();
        gld_lds16(gA0, lA0);
        gld_lds16(gA1, lA1);
        gld_lds16(gB0, lB0);
        gld_lds16(gB1, lB1);
        gA0 += 32; gA1 += 32; gB0 += 32; gB1 += 32;
        __syncthreads();
        short8 af[4], bfr[4];
#pragma unroll
        for (int mi = 0; mi < 4; ++mi)
            af[mi] = *(const short8*)(At + (wm * 64 + mi * 16 + l15) * 32 + lq * 8);
#pragma unroll
        for (int nj = 0; nj < 4; ++nj)
            bfr[nj] = *(const short8*)(Bt + (wn * 64 + nj * 16 + l15) * 32 + lq * 8);
#pragma unroll
        for (int mi = 0; mi < 4; ++mi)
#pragma unroll
            for (int nj = 0; nj < 4; ++nj)
                acc[mi][nj] = __builtin_amdgcn_mfma_f32_16x16x32_bf16(af[mi], bfr[nj], acc[mi][nj], 0, 0, 0);
    }

    // epilogue: col c = wn*64 + nj*16 + l15 -> t = t0+wn, jb = nj, b16 = l15
#pragma unroll
    for (int mi = 0; mi < 4; ++mi) {
#pragma unroll
        for (int rr = 0; rr < 4; ++rr) {
            int np = n0 + wm * 64 + mi * 16 + lq * 4 + rr;
            float bs = bias[np];
#pragma unroll
            for (int nj = 0; nj < 4; ++nj) {
                size_t idx = ((((size_t)(t0 + wn)) * 4 + nj) * 4096 + np) * 16 + l15;
                Xg[idx] = f2bf(acc[mi][nj][rr] + bs);
            }
        }
    }
}

// --- phase 2: persistent recurrence (R5 + epoch-counter barrier).
// 128 blocks x 512 thr: jb=blk&3 (16 batches), ibb=blk>>2 (n' rows
// [ibb*128,+128) = 32 hids x 4 gates). Wave w: rows ibb*128+w*16+[0,16).
// Lane (lq,l15): acc[rr] = gate-rr preact for hid=ibb*32+w*4+lq, b=jb*16+l15.
__global__ __launch_bounds__(512, 2) void k_rec(const unsigned short* __restrict__ Wh,
                                                const unsigned short* __restrict__ Xg,
                                                const float* __restrict__ c0,
                                                unsigned short* __restrict__ h0buf,
                                                unsigned short* __restrict__ h1buf) {
    const int blk = blockIdx.x;
    const int jb  = blk & 3;
    const int ibb = blk >> 2;
    const int tid = threadIdx.x;
    const int w   = tid >> 6;
    const int l   = tid & 63;
    const int l15 = l & 15, lq = l >> 4;

    __shared__ unsigned short hTl[16 * 1032];   // [b16][k=1024], stride 1032
    __shared__ unsigned short hTr[16 * 36];     // h transpose [b16][hid32], pad 36

    // Persistent A-fragments: rows n' = ibb*128 + w*16 + l15, all K.
    // (R3 evidence: pinned frags land in AGPRs; MFMA reads AGPR A-ops free.)
    short8 afrag[32];
    {
        const unsigned short* wrow = Wh + (size_t)(ibb * 128 + w * 16 + l15) * 1024;
#pragma unroll
        for (int ks = 0; ks < 32; ++ks)
            afrag[ks] = *(const short8*)(wrow + ks * 32 + lq * 8);
#pragma unroll
        for (int ks = 0; ks < 32; ++ks)
            asm volatile("" : "+v"(afrag[ks]));
    }

    const int hid = ibb * 32 + w * 4 + lq;     // this lane's hidden unit
    float c = c0[hid];

    // h staging mapping: thread -> (batch row sb, u64 lane sln)
    const int sb = tid >> 5, sln = tid & 31;
    const unsigned long long* poll0 =
        (const unsigned long long*)h0buf + (size_t)(jb * 16 + sb) * 256;
    const unsigned long long* poll1 =
        (const unsigned long long*)h1buf + (size_t)(jb * 16 + sb) * 256;

    unsigned* ctr = &g_bars[jb * 32];          // this group's epoch counter

    // Xg fixed part: (( (t*4+jb)*4096 + ibb*128 + w*16 + lq*4 + rr )*16 + l15
    const size_t xg_fix = ((size_t)ibb * 128 + w * 16 + lq * 4) * 16 + l15;

    float xg[4];
#pragma unroll
    for (int rr = 0; rr < 4; ++rr)
        xg[rr] = bf2f(Xg[((size_t)jb * 4096 + rr) * 16 + xg_fix]);   // t = 0

    for (int t = 0; t < SEQL; ++t) {
        const unsigned long long* src64 = (t & 1) ? poll1 : poll0;
        unsigned short* hdst = (t & 1) ? h0buf : h1buf;

        // --- barrier wait: all 32 producers of h_t have bumped the counter ---
        if (tid == 0) {
            unsigned tgt = 32u * (unsigned)t;
            while (__hip_atomic_load(ctr, __ATOMIC_RELAXED,
                                     __HIP_MEMORY_SCOPE_AGENT) < tgt)
                __builtin_amdgcn_s_sleep(2);
        }
        __syncthreads();

        // --- stage h slice (16 batches x 1024 k) into LDS, coalesced ---
        {
            unsigned long long tmp[8];
#pragma unroll
            for (int p = 0; p < 8; ++p)
                tmp[p] = __hip_atomic_load(src64 + p * 32 + sln,
                                           __ATOMIC_RELAXED, __HIP_MEMORY_SCOPE_AGENT);
#pragma unroll
            for (int p = 0; p < 8; ++p)
                *(unsigned long long*)(&hTl[sb * 1032 + (p * 32 + sln) * 4]) = tmp[p];
        }
        __syncthreads();

        // --- MFMA over K=1024, two chains ---
        f32x4 acc0 = {0.f, 0.f, 0.f, 0.f}, acc1 = {0.f, 0.f, 0.f, 0.f};
#pragma unroll
        for (int ks = 0; ks < 32; ks += 2) {
            short8 b0 = *(const short8*)(&hTl[l15 * 1032 + ks * 32 + lq * 8]);
            short8 b1 = *(const short8*)(&hTl[l15 * 1032 + (ks + 1) * 32 + lq * 8]);
            acc0 = __builtin_amdgcn_mfma_f32_16x16x32_bf16(afrag[ks], b0, acc0, 0, 0, 0);
            acc1 = __builtin_amdgcn_mfma_f32_16x16x32_bf16(afrag[ks + 1], b1, acc1, 0, 0, 0);
        }

        // --- in-register gate math; h -> LDS transpose buffer ---
        {
            float pi = acc0[0] + acc1[0] + xg[0];
            float pf = acc0[1] + acc1[1] + xg[1];
            float po = acc0[2] + acc1[2] + xg[2];
            float pg = acc0[3] + acc1[3] + xg[3];
            float ig = sigmoidf_fast(pi);
            float fg = sigmoidf_fast(pf);
            float og = sigmoidf_fast(po);
            float gg = tanhf_fast(pg);
            c = fg * c + ig * gg;
            float hh = og * tanhf_fast(c);
            hTr[l15 * 36 + w * 4 + lq] = f2bf(hh);
        }
        __syncthreads();    // hTr complete; also protects hTl reuse next iter

        // --- coalesced h store: 16 rows x 64B, 128 threads x 8B ---
        if (tid < 128) {
            int row = tid >> 3, seg = tid & 7;
            unsigned long long v = *(const unsigned long long*)(&hTr[row * 36 + seg * 4]);
            unsigned long long* dst = (unsigned long long*)hdst +
                (((size_t)(jb * 16 + row) * 1024 + ibb * 32 + seg * 4) >> 2);
            __hip_atomic_store(dst, v, __ATOMIC_RELAXED, __HIP_MEMORY_SCOPE_AGENT);
        }
        asm volatile("s_waitcnt vmcnt(0)" ::: "memory");  // h stores at L3
        __syncthreads();                                   // all stores drained

        // --- epoch arrival (1 RMW per block), then Xg prefetch ---
        if (tid == 0)
            __hip_atomic_fetch_add(ctr, 1u, __ATOMIC_RELAXED,
                                   __HIP_MEMORY_SCOPE_AGENT);
        {
            int tn = (t < SEQL - 1) ? t + 1 : t;
            size_t base = (((size_t)tn * 4 + jb) * 4096) * 16 + xg_fix;
#pragma unroll
            for (int rr = 0; rr < 4; ++rr)
                xg[rr] = bf2f(Xg[base + (size_t)rr * 16]);
        }
    }
    // t=511 writes hdst = h0buf: final h in h0buf
}

// --- output: out[b][o] = sum_k h[b][k] * w[o][k]
__global__ __launch_bounds__(256) void k_out(const unsigned short* __restrict__ hT,
                                             const float* __restrict__ wT,
                                             float* __restrict__ out) {
    const int b = blockIdx.x;
    const int tid = threadIdx.x;
    __shared__ float hs[1024];
#pragma unroll
    for (int p = 0; p < 4; ++p)
        hs[p * 256 + tid] = bf2f(hT[b * 1024 + p * 256 + tid]);
    __syncthreads();
    float a0 = 0.f, a1 = 0.f;
    for (int k = 0; k < 1024; ++k) {
        float hv = hs[k];
        a0 = fmaf(hv, wT[k * 512 + tid], a0);
        a1 = fmaf(hv, wT[k * 512 + 256 + tid], a1);
    }
    out[b * 512 + tid] = a0;
    out[b * 512 + 256 + tid] = a1;
}

extern "C" void kernel_launch(void* const* d_in, const int* in_sizes, int n_in,
                              void* d_out, int out_size, void* d_ws, size_t ws_size,
                              hipStream_t stream) {
    const float* X    = (const float*)d_in[0];
    const float* c0   = (const float*)d_in[1];
    const float* h0   = (const float*)d_in[2];
    const float* w_hi = (const float*)d_in[3];
    const float* w_xi = (const float*)d_in[4];
    const float* b_hi = (const float*)d_in[5];
    const float* b_xi = (const float*)d_in[6];
    const float* w_hf = (const float*)d_in[7];
    const float* w_xf = (const float*)d_in[8];
    const float* b_hf = (const float*)d_in[9];
    const float* b_xf = (const float*)d_in[10];
    const float* w_ho = (const float*)d_in[11];
    const float* w_xo = (const float*)d_in[12];
    const float* b_ho = (const float*)d_in[13];
    const float* b_xo = (const float*)d_in[14];
    const float* w_hg = (const float*)d_in[15];
    const float* w_xg = (const float*)d_in[16];
    const float* b_hg = (const float*)d_in[17];
    const float* b_xg = (const float*)d_in[18];
    const float* w    = (const float*)d_in[19];

    // workspace layout (16B aligned); ~338 MiB
    char* ws = (char*)d_ws;
    size_t off = 0;
    unsigned short* Xg  = (unsigned short*)(ws + off); off += (size_t)512 * 4096 * 64 * 2;
    unsigned short* Whp = (unsigned short*)(ws + off); off += (size_t)4096 * 1024 * 2;
    unsigned short* Wxp = (unsigned short*)(ws + off); off += (size_t)4096 * 1024 * 2;
    unsigned short* Xb  = (unsigned short*)(ws + off); off += (size_t)64 * 512 * 1024 * 2;
    float*          bias= (float*)(ws + off);          off += (size_t)4096 * 4;
    float*          wT  = (float*)(ws + off);          off += (size_t)1024 * 512 * 4;
    unsigned short* hT0 = (unsigned short*)(ws + off); off += (size_t)64 * 1024 * 2;
    unsigned short* hT1 = (unsigned short*)(ws + off); off += (size_t)64 * 1024 * 2;
    if (ws_size < off) return;

    k_pack_w<<<4096, 256, 0, stream>>>(w_hi, w_hf, w_ho, w_hg, Whp);
    k_pack_w<<<4096, 256, 0, stream>>>(w_xi, w_xf, w_xo, w_xg, Wxp);
    k_misc<<<(4096 + 65536 + 524288 + 128 + 255) / 256, 256, 0, stream>>>(
        b_hi, b_xi, b_hf, b_xf, b_ho, b_xo, b_hg, b_xg, h0, w, bias, hT0, wT);
    k_convert_x<<<33554432 / 4 / 256, 256, 0, stream>>>(X, Xb);

    k_xgemm<<<dim3(256, 32), 256, 0, stream>>>(Wxp, Xb, bias, Xg);

    void* args[] = {(void*)&Whp, (void*)&Xg, (void*)&c0, (void*)&hT0, (void*)&hT1};
    hipLaunchCooperativeKernel((void*)k_rec, dim3(128), dim3(512), args, 0, stream);

    k_out<<<64, 256, 0, stream>>>(hT0, wT, (float*)d_out);
}